// Round 1
// baseline (582.625 us; speedup 1.0000x reference)
//
#include <hip/hip_runtime.h>

#define BATCH 8
#define NPOS 784          // H*W per batch
#define CH 512
#define DI 4096
#define CHUNKS 98         // per batch
#define PPC 8             // positions per chunk (CHUNKS*PPC == NPOS)
#define PHI_LEN 8705      // 1 + 512 + 2*4096
#define S_FLOATS (BATCH * 2 * 2049 * 2)   // spectral accumulators (re,im), k=0..2048
#define PHI_OFF S_FLOATS

__device__ __forceinline__ float2 cmul(float2 a, float2 b) {
  return make_float2(a.x * b.x - a.y * b.y, a.x * b.y + a.y * b.x);
}

// In-place 4096-point DIT FFT; input in bit-reversed order, output natural.
// Twiddle table W[r] supplies the kernel sign (forward: e^{-2pi i r/N}).
__device__ inline void fft4096(float2* Z, const float2* W, int tid) {
  for (int s = 1; s <= 12; ++s) {
    __syncthreads();
    const int half = 1 << (s - 1);
    const int tsh = 12 - s;
    #pragma unroll
    for (int q = 0; q < 8; ++q) {
      int bidx = tid + q * 256;
      int j = bidx & (half - 1);
      int i1 = ((bidx >> (s - 1)) << s) + j;
      int i2 = i1 + half;
      float2 w = W[j << tsh];
      float2 u = Z[i1];
      float2 v = Z[i2];
      float2 t = cmul(w, v);
      Z[i1] = make_float2(u.x + t.x, u.y + t.y);
      Z[i2] = make_float2(u.x - t.x, u.y - t.y);
    }
  }
  __syncthreads();
}

// Stage 1: per chunk of 8 positions -> build sketches in LDS, FFT, accumulate
// spectral products into global S via atomics. Also accumulates channel sums
// for the first-order term.
__global__ __launch_bounds__(256) void cbp_stage1(
    const float* __restrict__ x, const float* __restrict__ alpha,
    const int* __restrict__ h_idx, const int* __restrict__ s_bits,
    float* __restrict__ ws) {
  __shared__ float2 Z[DI];
  __shared__ float2 W[DI / 2];
  const int tid = threadIdx.x;

  // forward twiddles: W[r] = exp(-2*pi*i*r/4096)
  for (int r = tid; r < DI / 2; r += 256) {
    float ang = -1.5339807878856412e-3f * (float)r;  // -2*pi/4096 * r
    float sv, cv;
    sincosf(ang, &sv, &cv);
    W[r] = make_float2(cv, sv);
  }

  const int b = blockIdx.x / CHUNKS;
  const int ch = blockIdx.x % CHUNKS;

  const int c0 = tid * 2, c1 = tid * 2 + 1;
  // hash positions (pre-bit-reversed) and signs for this thread's 2 channels
  const int h0a = __brev((unsigned)h_idx[c0]) >> 20;
  const int h0b = __brev((unsigned)h_idx[c1]) >> 20;
  const int h1a = __brev((unsigned)h_idx[CH + c0]) >> 20;
  const int h1b = __brev((unsigned)h_idx[CH + c1]) >> 20;
  const int h2a = __brev((unsigned)h_idx[2 * CH + c0]) >> 20;
  const int h2b = __brev((unsigned)h_idx[2 * CH + c1]) >> 20;
  const float s0a = (float)(2 * s_bits[c0] - 1);
  const float s0b = (float)(2 * s_bits[c1] - 1);
  const float s1a = (float)(2 * s_bits[CH + c0] - 1);
  const float s1b = (float)(2 * s_bits[CH + c1] - 1);
  const float s2a = (float)(2 * s_bits[2 * CH + c0] - 1);
  const float s2b = (float)(2 * s_bits[2 * CH + c1] - 1);

  float2 acc2[8], acc3[8];
  #pragma unroll
  for (int j = 0; j < 8; ++j) {
    acc2[j] = make_float2(0.f, 0.f);
    acc3[j] = make_float2(0.f, 0.f);
  }
  float acc2x = 0.f;                 // k=2048, order2 (real)
  float2 acc3x = make_float2(0.f, 0.f);
  float xsa = 0.f, xsb = 0.f;        // channel sums for first-order term

  for (int i = 0; i < PPC; ++i) {
    const int n = b * NPOS + ch * PPC + i;
    const float* xp = x + (size_t)n * CH;
    const float xa = xp[c0];
    const float xb = xp[c1];
    xsa += xa;
    xsb += xb;

    // ---- FFT 1: Z = sk0 + i*sk1 ----
    __syncthreads();  // previous iteration readers done
    #pragma unroll
    for (int q = 0; q < 16; ++q) Z[tid + q * 256] = make_float2(0.f, 0.f);
    __syncthreads();
    atomicAdd(&Z[h0a].x, xa * s0a);
    atomicAdd(&Z[h0b].x, xb * s0b);
    atomicAdd(&Z[h1a].y, xa * s1a);
    atomicAdd(&Z[h1b].y, xb * s1b);
    fft4096(Z, W, tid);

    float2 p2s[8];
    #pragma unroll
    for (int j = 0; j < 8; ++j) {
      const int k = tid + j * 256;            // k in [0, 2048)
      const int m = (DI - k) & (DI - 1);
      float2 Zk = Z[k];
      float2 Zm = Z[m];
      // X0 = (Z[k] + conj(Z[N-k]))/2 ; X1 = (Z[k] - conj(Z[N-k]))/(2i)
      float2 X0 = make_float2(0.5f * (Zk.x + Zm.x), 0.5f * (Zk.y - Zm.y));
      float2 X1 = make_float2(0.5f * (Zk.y + Zm.y), -0.5f * (Zk.x - Zm.x));
      float2 P2 = cmul(X0, X1);
      p2s[j] = P2;
      acc2[j].x += P2.x;
      acc2[j].y += P2.y;
    }
    float p2xr = 0.f;
    if (tid == 0) {  // k = 2048: X0 = Re(Z), X1 = Im(Z), both real
      float2 Zk = Z[2048];
      p2xr = Zk.x * Zk.y;
      acc2x += p2xr;
    }

    // ---- FFT 2: Z = sk2 (real) ----
    __syncthreads();
    #pragma unroll
    for (int q = 0; q < 16; ++q) Z[tid + q * 256] = make_float2(0.f, 0.f);
    __syncthreads();
    atomicAdd(&Z[h2a].x, xa * s2a);
    atomicAdd(&Z[h2b].x, xb * s2b);
    fft4096(Z, W, tid);

    #pragma unroll
    for (int j = 0; j < 8; ++j) {
      const int k = tid + j * 256;
      float2 X2 = Z[k];
      float2 P3 = cmul(p2s[j], X2);
      acc3[j].x += P3.x;
      acc3[j].y += P3.y;
    }
    if (tid == 0) {
      float2 X2 = Z[2048];
      acc3x.x += p2xr * X2.x;
      acc3x.y += p2xr * X2.y;
    }
  }

  // ---- writeback: atomic accumulate spectral partial sums ----
  float* S = ws;
  #pragma unroll
  for (int j = 0; j < 8; ++j) {
    const int k = tid + j * 256;
    float* p2p = S + ((size_t)(b * 2 + 0) * 2049 + k) * 2;
    atomicAdd(p2p, acc2[j].x);
    atomicAdd(p2p + 1, acc2[j].y);
    float* p3p = S + ((size_t)(b * 2 + 1) * 2049 + k) * 2;
    atomicAdd(p3p, acc3[j].x);
    atomicAdd(p3p + 1, acc3[j].y);
  }
  if (tid == 0) {
    float* p2p = S + ((size_t)(b * 2 + 0) * 2049 + 2048) * 2;
    atomicAdd(p2p, acc2x);
    float* p3p = S + ((size_t)(b * 2 + 1) * 2049 + 2048) * 2;
    atomicAdd(p3p, acc3x.x);
    atomicAdd(p3p + 1, acc3x.y);
  }

  // first-order term: alpha1 * mean(x) over spatial, per channel
  const float sc1 = alpha[1] * (1.0f / (float)NPOS);
  float* phi = ws + PHI_OFF;
  atomicAdd(&phi[(size_t)b * PHI_LEN + 1 + c0], xsa * sc1);
  atomicAdd(&phi[(size_t)b * PHI_LEN + 1 + c1], xsb * sc1);
}

// Stage 2: one block per (batch, order): Hermitian reconstruct + inverse FFT,
// scale by alpha/(DI*NPOS), write into phi staging.
__global__ __launch_bounds__(256) void cbp_stage2(
    const float* __restrict__ ws_in, const float* __restrict__ alpha,
    float* __restrict__ ws_phi) {
  __shared__ float2 Z[DI];
  __shared__ float2 W[DI / 2];
  const int tid = threadIdx.x;

  // inverse twiddles: W[r] = exp(+2*pi*i*r/4096)
  for (int r = tid; r < DI / 2; r += 256) {
    float ang = 1.5339807878856412e-3f * (float)r;
    float sv, cv;
    sincosf(ang, &sv, &cv);
    W[r] = make_float2(cv, sv);
  }

  const int b = blockIdx.x >> 1;
  const int t = blockIdx.x & 1;
  const float* Sp = ws_in + (size_t)(b * 2 + t) * 2049 * 2;

  for (int k = tid; k <= 2048; k += 256) {
    float re = Sp[k * 2];
    float im = Sp[k * 2 + 1];
    Z[__brev((unsigned)k) >> 20] = make_float2(re, im);
    if (k > 0 && k < 2048) {
      Z[__brev((unsigned)(DI - k)) >> 20] = make_float2(re, -im);
    }
  }
  fft4096(Z, W, tid);  // computes N * ifft (positive-exponent DFT)

  const float scale = alpha[2 + t] / ((float)DI * (float)NPOS);
  float* out = ws_phi + (size_t)b * PHI_LEN + 513 + t * DI;
  for (int d = tid; d < DI; d += 256) out[d] = Z[d].x * scale;
}

// Stage 3: one block per batch: signed sqrt + L2 normalize -> d_out.
__global__ __launch_bounds__(256) void cbp_stage3(
    const float* __restrict__ ws_phi, const float* __restrict__ alpha,
    float* __restrict__ out) {
  __shared__ float red[4];
  const int b = blockIdx.x;
  const int tid = threadIdx.x;
  const float* pr = ws_phi + (size_t)b * PHI_LEN;
  const float a0 = alpha[0];

  float w[35];
  float ssum = 0.f;
  #pragma unroll
  for (int j = 0; j < 35; ++j) {
    const int idx = tid + j * 256;
    float wv = 0.f;
    if (idx < PHI_LEN) {
      float v = (idx == 0) ? a0 : pr[idx];
      float sq = sqrtf(fabsf(v) + 1e-12f);
      wv = (v > 0.f) ? sq : ((v < 0.f) ? -sq : 0.f);
    }
    w[j] = wv;
    ssum += wv * wv;
  }
  // block reduction (4 waves of 64)
  for (int off = 32; off > 0; off >>= 1) ssum += __shfl_down(ssum, off);
  if ((tid & 63) == 0) red[tid >> 6] = ssum;
  __syncthreads();
  const float tot = red[0] + red[1] + red[2] + red[3];
  const float inv = 1.0f / sqrtf(tot);

  #pragma unroll
  for (int j = 0; j < 35; ++j) {
    const int idx = tid + j * 256;
    if (idx < PHI_LEN) out[(size_t)b * PHI_LEN + idx] = w[j] * inv;
  }
}

extern "C" void kernel_launch(void* const* d_in, const int* in_sizes, int n_in,
                              void* d_out, int out_size, void* d_ws,
                              size_t ws_size, hipStream_t stream) {
  const float* x = (const float*)d_in[0];
  const float* alpha = (const float*)d_in[1];
  const int* h_idx = (const int*)d_in[2];
  const int* s_bits = (const int*)d_in[3];
  float* out = (float*)d_out;
  float* ws = (float*)d_ws;

  // zero spectral accumulators + phi staging (atomically accumulated)
  const size_t zero_bytes = (size_t)(S_FLOATS + BATCH * PHI_LEN) * sizeof(float);
  hipMemsetAsync(d_ws, 0, zero_bytes, stream);

  cbp_stage1<<<dim3(BATCH * CHUNKS), dim3(256), 0, stream>>>(x, alpha, h_idx,
                                                             s_bits, ws);
  cbp_stage2<<<dim3(BATCH * 2), dim3(256), 0, stream>>>(ws, alpha,
                                                        ws + PHI_OFF);
  cbp_stage3<<<dim3(BATCH), dim3(256), 0, stream>>>(ws + PHI_OFF, alpha, out);
}

// Round 2
// 258.655 us; speedup vs baseline: 2.2525x; 2.2525x over previous
//
#include <hip/hip_runtime.h>

#define BATCH 8
#define NPOS 784          // H*W per batch
#define CH 512
#define DI 4096
#define CHUNKS 98         // per batch
#define PPC 8             // positions per chunk
#define PHI_LEN 8705      // 1 + 512 + 2*4096
#define S_FLOATS (BATCH * 2 * 2049 * 2)
#define PHI_OFF S_FLOATS

__device__ __forceinline__ float2 cmul(float2 a, float2 b) {
  return make_float2(a.x * b.x - a.y * b.y, a.x * b.y + a.y * b.x);
}

// forward DFT4 (w4 = -i): outputs y0..y3 into a,b,c,d
__device__ __forceinline__ void dft4(float2& a, float2& b, float2& c, float2& d) {
  float t0x = a.x + c.x, t0y = a.y + c.y;
  float t1x = a.x - c.x, t1y = a.y - c.y;
  float t2x = b.x + d.x, t2y = b.y + d.y;
  float t3x = b.x - d.x, t3y = b.y - d.y;
  a = make_float2(t0x + t2x, t0y + t2y);
  c = make_float2(t0x - t2x, t0y - t2y);
  b = make_float2(t1x + t3y, t1y - t3x);   // t1 - i*t3
  d = make_float2(t1x - t3y, t1y + t3x);   // t1 + i*t3
}

// forward 16-point DFT, input v[t] natural time order.
// On exit, slot (k1 + 4*k2) holds bin (k2 + 4*k1): caller permutes on store
// with slot = (k>>2) + ((k&3)<<2) for bin k.
__device__ __forceinline__ void dft16(float2 v[16]) {
  dft4(v[0], v[4], v[8], v[12]);
  dft4(v[1], v[5], v[9], v[13]);
  dft4(v[2], v[6], v[10], v[14]);
  dft4(v[3], v[7], v[11], v[15]);
  const float C1 = 0.92387953251128674f, S1 = 0.38268343236508977f;
  const float R = 0.70710678118654752f;
  v[5]  = cmul(v[5],  make_float2( C1, -S1));   // w16^1
  v[9]  = cmul(v[9],  make_float2(  R,  -R));   // w16^2
  v[13] = cmul(v[13], make_float2( S1, -C1));   // w16^3
  v[6]  = cmul(v[6],  make_float2(  R,  -R));   // w16^2
  v[10] = cmul(v[10], make_float2(0.f, -1.f));  // w16^4
  v[14] = cmul(v[14], make_float2( -R,  -R));   // w16^6
  v[7]  = cmul(v[7],  make_float2( S1, -C1));   // w16^3
  v[11] = cmul(v[11], make_float2( -R,  -R));   // w16^6
  v[15] = cmul(v[15], make_float2(-C1,  S1));   // w16^9
  dft4(v[0], v[1], v[2], v[3]);
  dft4(v[4], v[5], v[6], v[7]);
  dft4(v[8], v[9], v[10], v[11]);
  dft4(v[12], v[13], v[14], v[15]);
}

// multiply v[u] by w^u, u=0..15, log-depth power tree
__device__ __forceinline__ void twiddle16(float2 v[16], float2 w) {
  float2 w2 = cmul(w, w);
  float2 w3 = cmul(w2, w);
  float2 w4 = cmul(w2, w2);
  float2 w5 = cmul(w3, w2);
  float2 w6 = cmul(w3, w3);
  float2 w7 = cmul(w4, w3);
  float2 w8 = cmul(w4, w4);
  float2 w9 = cmul(w5, w4);
  float2 w10 = cmul(w5, w5);
  float2 w11 = cmul(w6, w5);
  float2 w12 = cmul(w6, w6);
  float2 w13 = cmul(w7, w6);
  float2 w14 = cmul(w7, w7);
  float2 w15 = cmul(w8, w7);
  v[1] = cmul(v[1], w);    v[2] = cmul(v[2], w2);   v[3] = cmul(v[3], w3);
  v[4] = cmul(v[4], w4);   v[5] = cmul(v[5], w5);   v[6] = cmul(v[6], w6);
  v[7] = cmul(v[7], w7);   v[8] = cmul(v[8], w8);   v[9] = cmul(v[9], w9);
  v[10] = cmul(v[10], w10); v[11] = cmul(v[11], w11); v[12] = cmul(v[12], w12);
  v[13] = cmul(v[13], w13); v[14] = cmul(v[14], w14); v[15] = cmul(v[15], w15);
}

// 4096-pt forward FFT, radix-16^3, input scattered digit-reversed+swizzled,
// output natural order at phys(i) = i ^ ((i>>4)&15).
__device__ __forceinline__ void fft_stages(float2* Z, int tid, float2 w1b,
                                           float2 w2b) {
  const int tl = tid & 15;
  const int g16 = tid << 4;
  const int b1 = (tid >> 4) << 8;
  const int base2 = (tid & 240) | (tl ^ ((tid >> 4) & 15));
  __syncthreads();  // scatter done
  {  // stage 0: contiguous 16-blocks, twiddle-free
    float2 v[16];
    #pragma unroll
    for (int u = 0; u < 16; ++u) v[u] = Z[g16 + (u ^ tl)];
    dft16(v);
    #pragma unroll
    for (int k = 0; k < 16; ++k)
      Z[g16 + (k ^ tl)] = v[(k >> 2) + ((k & 3) << 2)];
  }
  __syncthreads();
  {  // stage 1: stride 16 within 256-blocks, twiddle w256^{j*u}
    float2 v[16];
    #pragma unroll
    for (int u = 0; u < 16; ++u) v[u] = Z[b1 + (u << 4) + (tl ^ u)];
    twiddle16(v, w1b);
    dft16(v);
    #pragma unroll
    for (int k = 0; k < 16; ++k)
      Z[b1 + (k << 4) + (tl ^ k)] = v[(k >> 2) + ((k & 3) << 2)];
  }
  __syncthreads();
  {  // stage 2: stride 256, twiddle w4096^{t*u}
    float2 v[16];
    #pragma unroll
    for (int u = 0; u < 16; ++u) v[u] = Z[(u << 8) + base2];
    twiddle16(v, w2b);
    dft16(v);
    #pragma unroll
    for (int k = 0; k < 16; ++k)
      Z[(k << 8) + base2] = v[(k >> 2) + ((k & 3) << 2)];
  }
  __syncthreads();
}

__global__ __launch_bounds__(256) void cbp_stage1(
    const float* __restrict__ x, const float* __restrict__ alpha,
    const int* __restrict__ h_idx, const int* __restrict__ s_bits,
    float* __restrict__ ws) {
  __shared__ float2 Z[DI];
  float* Zf = (float*)Z;
  const int tid = threadIdx.x;
  const int bb = blockIdx.x / CHUNKS;
  const int ch = blockIdx.x % CHUNKS;

  // map hash -> phys(digitrev16(h))
  auto mapidx = [](int h) {
    int r = ((h & 15) << 8) | (h & 240) | (h >> 8);
    return r ^ ((r >> 4) & 15);
  };
  const int c0 = tid * 2, c1 = c0 + 1;
  const int h0a = mapidx(h_idx[c0]);
  const int h0b = mapidx(h_idx[c1]);
  const int h1a = mapidx(h_idx[CH + c0]);
  const int h1b = mapidx(h_idx[CH + c1]);
  const int h2a = mapidx(h_idx[2 * CH + c0]);
  const int h2b = mapidx(h_idx[2 * CH + c1]);
  const float s0a = (float)(2 * s_bits[c0] - 1);
  const float s0b = (float)(2 * s_bits[c1] - 1);
  const float s1a = (float)(2 * s_bits[CH + c0] - 1);
  const float s1b = (float)(2 * s_bits[CH + c1] - 1);
  const float s2a = (float)(2 * s_bits[2 * CH + c0] - 1);
  const float s2b = (float)(2 * s_bits[2 * CH + c1] - 1);

  const int tl = tid & 15;
  const int base2 = (tid & 240) | (tl ^ ((tid >> 4) & 15));
  float sv, cv;
  __sincosf(-2.4543692606170259e-2f * (float)tl, &sv, &cv);  // -2pi/256 * j
  const float2 w1b = make_float2(cv, sv);
  __sincosf(-1.5339807878856412e-3f * (float)tid, &sv, &cv); // -2pi/4096 * t
  const float2 w2b = make_float2(cv, sv);

  float2 acc2[8], acc3[8], p2e[8], p2o[8];
  #pragma unroll
  for (int j = 0; j < 8; ++j) {
    acc2[j] = make_float2(0.f, 0.f);
    acc3[j] = make_float2(0.f, 0.f);
  }
  float acc2x = 0.f, acc3x = 0.f, p2xe = 0.f, p2xo = 0.f;
  float xsa = 0.f, xsb = 0.f;

  // initial zero
  #pragma unroll
  for (int q = 0; q < 16; ++q) Z[tid + (q << 8)] = make_float2(0.f, 0.f);
  __syncthreads();

  for (int ip = 0; ip < 4; ++ip) {
    const int n0 = bb * NPOS + ch * PPC + ip * 2;
    const float2 xv0 = *(const float2*)(x + (size_t)n0 * CH + c0);
    const float2 xv1 = *(const float2*)(x + (size_t)(n0 + 1) * CH + c0);
    xsa += xv0.x + xv1.x;
    xsb += xv0.y + xv1.y;

    // ---- FFT A: sk0(even) + i*sk1(even) ----
    atomicAdd(&Zf[2 * h0a], xv0.x * s0a);
    atomicAdd(&Zf[2 * h0b], xv0.y * s0b);
    atomicAdd(&Zf[2 * h1a + 1], xv0.x * s1a);
    atomicAdd(&Zf[2 * h1b + 1], xv0.y * s1b);
    fft_stages(Z, tid, w1b, w2b);
    #pragma unroll
    for (int jj = 0; jj < 8; ++jj) {
      const int k = tid + (jj << 8);
      const int ak = (jj << 8) + base2;
      const int m = (DI - k) & (DI - 1);
      const int am = m ^ ((m >> 4) & 15);
      float2 Zk = Z[ak], Zm = Z[am];
      Z[ak] = make_float2(0.f, 0.f);
      Z[am] = make_float2(0.f, 0.f);
      float2 X0 = make_float2(0.5f * (Zk.x + Zm.x), 0.5f * (Zk.y - Zm.y));
      float2 X1 = make_float2(0.5f * (Zk.y + Zm.y), -0.5f * (Zk.x - Zm.x));
      float2 P2 = cmul(X0, X1);
      p2e[jj] = P2;
      acc2[jj].x += P2.x;
      acc2[jj].y += P2.y;
    }
    if (tid == 0) {
      float2 Zq = Z[2048];
      Z[2048] = make_float2(0.f, 0.f);
      p2xe = Zq.x * Zq.y;
      acc2x += p2xe;
    }
    __syncthreads();

    // ---- FFT B: sk0(odd) + i*sk1(odd) ----
    atomicAdd(&Zf[2 * h0a], xv1.x * s0a);
    atomicAdd(&Zf[2 * h0b], xv1.y * s0b);
    atomicAdd(&Zf[2 * h1a + 1], xv1.x * s1a);
    atomicAdd(&Zf[2 * h1b + 1], xv1.y * s1b);
    fft_stages(Z, tid, w1b, w2b);
    #pragma unroll
    for (int jj = 0; jj < 8; ++jj) {
      const int k = tid + (jj << 8);
      const int ak = (jj << 8) + base2;
      const int m = (DI - k) & (DI - 1);
      const int am = m ^ ((m >> 4) & 15);
      float2 Zk = Z[ak], Zm = Z[am];
      Z[ak] = make_float2(0.f, 0.f);
      Z[am] = make_float2(0.f, 0.f);
      float2 X0 = make_float2(0.5f * (Zk.x + Zm.x), 0.5f * (Zk.y - Zm.y));
      float2 X1 = make_float2(0.5f * (Zk.y + Zm.y), -0.5f * (Zk.x - Zm.x));
      float2 P2 = cmul(X0, X1);
      p2o[jj] = P2;
      acc2[jj].x += P2.x;
      acc2[jj].y += P2.y;
    }
    if (tid == 0) {
      float2 Zq = Z[2048];
      Z[2048] = make_float2(0.f, 0.f);
      p2xo = Zq.x * Zq.y;
      acc2x += p2xo;
    }
    __syncthreads();

    // ---- FFT C: sk2(even) + i*sk2(odd) ----
    atomicAdd(&Zf[2 * h2a], xv0.x * s2a);
    atomicAdd(&Zf[2 * h2a + 1], xv1.x * s2a);
    atomicAdd(&Zf[2 * h2b], xv0.y * s2b);
    atomicAdd(&Zf[2 * h2b + 1], xv1.y * s2b);
    fft_stages(Z, tid, w1b, w2b);
    #pragma unroll
    for (int jj = 0; jj < 8; ++jj) {
      const int k = tid + (jj << 8);
      const int ak = (jj << 8) + base2;
      const int m = (DI - k) & (DI - 1);
      const int am = m ^ ((m >> 4) & 15);
      float2 Zk = Z[ak], Zm = Z[am];
      Z[ak] = make_float2(0.f, 0.f);
      Z[am] = make_float2(0.f, 0.f);
      float2 Xa = make_float2(0.5f * (Zk.x + Zm.x), 0.5f * (Zk.y - Zm.y));
      float2 Xb = make_float2(0.5f * (Zk.y + Zm.y), -0.5f * (Zk.x - Zm.x));
      float2 Pa = cmul(p2e[jj], Xa);
      float2 Pb = cmul(p2o[jj], Xb);
      acc3[jj].x += Pa.x + Pb.x;
      acc3[jj].y += Pa.y + Pb.y;
    }
    if (tid == 0) {
      float2 Zq = Z[2048];
      Z[2048] = make_float2(0.f, 0.f);
      acc3x += p2xe * Zq.x + p2xo * Zq.y;
    }
    __syncthreads();
  }

  // ---- writeback ----
  float* S = ws;
  #pragma unroll
  for (int jj = 0; jj < 8; ++jj) {
    const int k = tid + (jj << 8);
    float* p2p = S + ((size_t)(bb * 2 + 0) * 2049 + k) * 2;
    atomicAdd(p2p, acc2[jj].x);
    atomicAdd(p2p + 1, acc2[jj].y);
    float* p3p = S + ((size_t)(bb * 2 + 1) * 2049 + k) * 2;
    atomicAdd(p3p, acc3[jj].x);
    atomicAdd(p3p + 1, acc3[jj].y);
  }
  if (tid == 0) {
    atomicAdd(S + ((size_t)(bb * 2 + 0) * 2049 + 2048) * 2, acc2x);
    atomicAdd(S + ((size_t)(bb * 2 + 1) * 2049 + 2048) * 2, acc3x);
  }

  const float sc1 = alpha[1] * (1.0f / (float)NPOS);
  float* phi = ws + PHI_OFF;
  atomicAdd(&phi[(size_t)bb * PHI_LEN + 1 + c0], xsa * sc1);
  atomicAdd(&phi[(size_t)bb * PHI_LEN + 1 + c1], xsb * sc1);
}

// ---------------- stage 2 (radix-2 FFT, 16 blocks, negligible) -------------
__device__ inline void fft4096_r2(float2* Z, const float2* W, int tid) {
  for (int s = 1; s <= 12; ++s) {
    __syncthreads();
    const int half = 1 << (s - 1);
    const int tsh = 12 - s;
    #pragma unroll
    for (int q = 0; q < 8; ++q) {
      int bidx = tid + q * 256;
      int j = bidx & (half - 1);
      int i1 = ((bidx >> (s - 1)) << s) + j;
      int i2 = i1 + half;
      float2 w = W[j << tsh];
      float2 u = Z[i1];
      float2 v = Z[i2];
      float2 t = cmul(w, v);
      Z[i1] = make_float2(u.x + t.x, u.y + t.y);
      Z[i2] = make_float2(u.x - t.x, u.y - t.y);
    }
  }
  __syncthreads();
}

__global__ __launch_bounds__(256) void cbp_stage2(
    const float* __restrict__ ws_in, const float* __restrict__ alpha,
    float* __restrict__ ws_phi) {
  __shared__ float2 Z[DI];
  __shared__ float2 W[DI / 2];
  const int tid = threadIdx.x;

  for (int r = tid; r < DI / 2; r += 256) {
    float ang = 1.5339807878856412e-3f * (float)r;  // +2pi/4096 * r (inverse)
    float sv, cv;
    sincosf(ang, &sv, &cv);
    W[r] = make_float2(cv, sv);
  }

  const int b = blockIdx.x >> 1;
  const int t = blockIdx.x & 1;
  const float* Sp = ws_in + (size_t)(b * 2 + t) * 2049 * 2;

  for (int k = tid; k <= 2048; k += 256) {
    float re = Sp[k * 2];
    float im = Sp[k * 2 + 1];
    Z[__brev((unsigned)k) >> 20] = make_float2(re, im);
    if (k > 0 && k < 2048) {
      Z[__brev((unsigned)(DI - k)) >> 20] = make_float2(re, -im);
    }
  }
  fft4096_r2(Z, W, tid);

  const float scale = alpha[2 + t] / ((float)DI * (float)NPOS);
  float* out = ws_phi + (size_t)b * PHI_LEN + 513 + t * DI;
  for (int d = tid; d < DI; d += 256) out[d] = Z[d].x * scale;
}

__global__ __launch_bounds__(256) void cbp_stage3(
    const float* __restrict__ ws_phi, const float* __restrict__ alpha,
    float* __restrict__ out) {
  __shared__ float red[4];
  const int b = blockIdx.x;
  const int tid = threadIdx.x;
  const float* pr = ws_phi + (size_t)b * PHI_LEN;
  const float a0 = alpha[0];

  float w[35];
  float ssum = 0.f;
  #pragma unroll
  for (int j = 0; j < 35; ++j) {
    const int idx = tid + j * 256;
    float wv = 0.f;
    if (idx < PHI_LEN) {
      float v = (idx == 0) ? a0 : pr[idx];
      float sq = sqrtf(fabsf(v) + 1e-12f);
      wv = (v > 0.f) ? sq : ((v < 0.f) ? -sq : 0.f);
    }
    w[j] = wv;
    ssum += wv * wv;
  }
  for (int off = 32; off > 0; off >>= 1) ssum += __shfl_down(ssum, off);
  if ((tid & 63) == 0) red[tid >> 6] = ssum;
  __syncthreads();
  const float tot = red[0] + red[1] + red[2] + red[3];
  const float inv = 1.0f / sqrtf(tot);

  #pragma unroll
  for (int j = 0; j < 35; ++j) {
    const int idx = tid + j * 256;
    if (idx < PHI_LEN) out[(size_t)b * PHI_LEN + idx] = w[j] * inv;
  }
}

extern "C" void kernel_launch(void* const* d_in, const int* in_sizes, int n_in,
                              void* d_out, int out_size, void* d_ws,
                              size_t ws_size, hipStream_t stream) {
  const float* x = (const float*)d_in[0];
  const float* alpha = (const float*)d_in[1];
  const int* h_idx = (const int*)d_in[2];
  const int* s_bits = (const int*)d_in[3];
  float* out = (float*)d_out;
  float* ws = (float*)d_ws;

  const size_t zero_bytes = (size_t)(S_FLOATS + BATCH * PHI_LEN) * sizeof(float);
  hipMemsetAsync(d_ws, 0, zero_bytes, stream);

  cbp_stage1<<<dim3(BATCH * CHUNKS), dim3(256), 0, stream>>>(x, alpha, h_idx,
                                                             s_bits, ws);
  cbp_stage2<<<dim3(BATCH * 2), dim3(256), 0, stream>>>(ws, alpha,
                                                        ws + PHI_OFF);
  cbp_stage3<<<dim3(BATCH), dim3(256), 0, stream>>>(ws + PHI_OFF, alpha, out);
}